// Round 2
// baseline (38.224 us; speedup 1.0000x reference)
//
#include <hip/hip_runtime.h>

#define N_PTS 512
#define DIM 128
#define TLMARGIN 1.0f

// One block per anchor row i. 512 threads.
// Phase 1: compute pdist row d[0..511] into LDS.
// Phase 2: negatives_inside (max over negatives; row_min is exactly 0).
// Phase 3: per-wave mining over positive columns j.
__global__ __launch_bounds__(512)
void triplet_rows(const float* __restrict__ inp,
                  const int* __restrict__ tgt,       // harness passes integers as int32
                  float* __restrict__ row_loss,
                  float* __restrict__ row_cnt) {
  const int i = blockIdx.x;
  const int tid = threadIdx.x;

  __shared__ float d[N_PTS];
  __shared__ int lab[N_PTS];
  __shared__ float rowi[DIM];
  __shared__ float redm[8];
  __shared__ float redl[8];
  __shared__ float redc[8];

  lab[tid] = tgt[tid];
  if (tid < DIM) rowi[tid] = inp[i * DIM + tid];
  __syncthreads();

  // ---- pdist row: d[tid] = max(sq_i + sq_tid - 2*dot(e_i, e_tid), 0), diag 0
  const float* rj = inp + tid * DIM;
  float dot = 0.f, sqi = 0.f, sqj = 0.f;
#pragma unroll
  for (int t = 0; t < DIM; t += 4) {
    float4 a = *reinterpret_cast<const float4*>(&rowi[t]);
    float4 b = *reinterpret_cast<const float4*>(&rj[t]);
    dot += a.x * b.x + a.y * b.y + a.z * b.z + a.w * b.w;
    sqi += a.x * a.x + a.y * a.y + a.z * a.z + a.w * a.w;
    sqj += b.x * b.x + b.y * b.y + b.z * b.z + b.w * b.w;
  }
  float pd = sqi + sqj - 2.0f * dot;
  pd = fmaxf(pd, 0.0f);
  if (tid == i) pd = 0.0f;
  d[tid] = pd;
  __syncthreads();

  const int li = lab[i];
  const int lane = tid & 63;
  const int wave = tid >> 6;

  // ---- negatives_inside: max over k with lab[k]!=li of d[k], floored at 0
  // (reference: max((d - row_min)*adjnot) + row_min with row_min == 0 exactly)
  float nm = (lab[tid] != li) ? d[tid] : 0.0f;
#pragma unroll
  for (int off = 32; off; off >>= 1) nm = fmaxf(nm, __shfl_xor(nm, off));
  if (lane == 0) redm[wave] = nm;
  __syncthreads();
  float neg_inside = redm[0];
#pragma unroll
  for (int w = 1; w < 8; ++w) neg_inside = fmaxf(neg_inside, redm[w]);

  // ---- mine positives: wave w handles j = w, w+8, ...
  float losssum = 0.0f;
  float pcount = 0.0f;
  for (int j = wave; j < N_PTS; j += 8) {
    if (j == i || lab[j] != li) continue;   // wave-uniform branch
    const float dj = d[j];
    float mn = __builtin_inff();
#pragma unroll
    for (int kk = 0; kk < N_PTS / 64; ++kk) {
      const int k = lane + kk * 64;
      const float dk = d[k];
      if (lab[k] != li && dk > dj) mn = fminf(mn, dk);
    }
#pragma unroll
    for (int off = 32; off; off >>= 1) mn = fminf(mn, __shfl_xor(mn, off));
    const float shn = (mn < __builtin_inff()) ? mn : neg_inside;
    losssum += fmaxf(TLMARGIN + dj - shn, 0.0f);
    pcount += 1.0f;
  }

  // ---- block reduce (every lane of a wave holds the same value)
  if (lane == 0) { redl[wave] = losssum; redc[wave] = pcount; }
  __syncthreads();
  if (tid == 0) {
    float ls = 0.0f, pc = 0.0f;
#pragma unroll
    for (int w = 0; w < 8; ++w) { ls += redl[w]; pc += redc[w]; }
    row_loss[i] = ls;
    row_cnt[i] = pc;
  }
}

__global__ __launch_bounds__(512)
void triplet_reduce(const float* __restrict__ row_loss,
                    const float* __restrict__ row_cnt,
                    float* __restrict__ out) {
  __shared__ float sl[8];
  __shared__ float sc[8];
  const int tid = threadIdx.x;
  float l = row_loss[tid];
  float c = row_cnt[tid];
#pragma unroll
  for (int off = 32; off; off >>= 1) {
    l += __shfl_xor(l, off);
    c += __shfl_xor(c, off);
  }
  const int lane = tid & 63, wave = tid >> 6;
  if (lane == 0) { sl[wave] = l; sc[wave] = c; }
  __syncthreads();
  if (tid == 0) {
    float L = 0.0f, C = 0.0f;
#pragma unroll
    for (int w = 0; w < 8; ++w) { L += sl[w]; C += sc[w]; }
    out[0] = L / C;
  }
}

extern "C" void kernel_launch(void* const* d_in, const int* in_sizes, int n_in,
                              void* d_out, int out_size, void* d_ws, size_t ws_size,
                              hipStream_t stream) {
  const float* inp = (const float*)d_in[0];
  const int* tgt = (const int*)d_in[1];
  float* out = (float*)d_out;

  float* row_loss = (float*)d_ws;          // 512 floats
  float* row_cnt  = (float*)d_ws + N_PTS;  // 512 floats

  triplet_rows<<<N_PTS, 512, 0, stream>>>(inp, tgt, row_loss, row_cnt);
  triplet_reduce<<<1, 512, 0, stream>>>(row_loss, row_cnt, out);
}

// Round 3
// 27.086 us; speedup vs baseline: 1.4112x; 1.4112x over previous
//
#include <hip/hip_runtime.h>

#define N_PTS 512
#define DIM 128
#define TLMARGIN 1.0f

// One block per anchor row i. 512 threads = 8 waves = 16 half-wave groups of 32.
// Phase 1 (coalesced): group g computes d[jt*16+g] cooperatively; lane l loads
//   inp[j*128 + 4l .. 4l+3] (float4) -> each wave instruction reads 1KB contiguous.
// Phase 2: negatives_inside (row_min is exactly 0 after clamp+diag-zero).
// Phase 3: compacted positive list (deterministic ballot+popcount order),
//   each wave mines its positives with a 64-lane strided scan + shuffle min.
__global__ __launch_bounds__(512)
void triplet_rows(const float* __restrict__ inp,
                  const int* __restrict__ tgt,
                  float* __restrict__ row_loss,
                  float* __restrict__ row_cnt) {
  const int i = blockIdx.x;
  const int tid = threadIdx.x;
  const int lane = tid & 63;
  const int wave = tid >> 6;
  const int g = tid >> 5;    // 0..15 half-wave group
  const int gl = tid & 31;   // lane within group

  __shared__ float d[N_PTS];
  __shared__ int lab[N_PTS];
  __shared__ float red[16];
  __shared__ unsigned long long pmask[8];
  __shared__ int plist[N_PTS];

  lab[tid] = tgt[tid];

  // anchor-row fragment in registers (same across all 16 groups)
  const float4 a = *reinterpret_cast<const float4*>(inp + i * DIM + (gl << 2));
  float sqi = a.x * a.x + a.y * a.y + a.z * a.z + a.w * a.w;
#pragma unroll
  for (int off = 16; off; off >>= 1) sqi += __shfl_xor(sqi, off);

  // ---- pdist row, coalesced
#pragma unroll 4
  for (int jt = 0; jt < N_PTS / 16; ++jt) {
    const int j = (jt << 4) + g;
    const float4 b = *reinterpret_cast<const float4*>(inp + j * DIM + (gl << 2));
    float dt = a.x * b.x + a.y * b.y + a.z * b.z + a.w * b.w;
    float sj = b.x * b.x + b.y * b.y + b.z * b.z + b.w * b.w;
#pragma unroll
    for (int off = 16; off; off >>= 1) {
      dt += __shfl_xor(dt, off);
      sj += __shfl_xor(sj, off);
    }
    float pd = sqi + sj - 2.0f * dt;
    pd = fmaxf(pd, 0.0f);
    if (j == i) pd = 0.0f;
    if (gl == 0) d[j] = pd;
  }
  __syncthreads();

  const int li = lab[i];

  // ---- negatives_inside = max over negatives of d (row_min == 0 exactly)
  float nm = (lab[tid] != li) ? d[tid] : 0.0f;
#pragma unroll
  for (int off = 32; off; off >>= 1) nm = fmaxf(nm, __shfl_xor(nm, off));
  if (lane == 0) red[wave] = nm;

  // ---- ballot positives, build deterministic compacted list
  const bool isPos = (lab[tid] == li) && (tid != i);
  const unsigned long long m = __ballot(isPos);
  if (lane == 0) pmask[wave] = m;
  __syncthreads();

  float neg_inside = red[0];
#pragma unroll
  for (int w = 1; w < 8; ++w) neg_inside = fmaxf(neg_inside, red[w]);

  int P = 0, rank = 0;
#pragma unroll
  for (int w = 0; w < 8; ++w) {
    const int c = __popcll(pmask[w]);
    if (w < wave) rank += c;
    P += c;
  }
  rank += __popcll(pmask[wave] & ((1ull << lane) - 1ull));
  if (isPos) plist[rank] = tid;
  __syncthreads();

  // ---- mine positives: wave w takes entries w, w+8, ...
  float losssum = 0.0f;
  float pcount = 0.0f;
  for (int p = wave; p < P; p += 8) {
    const int j = plist[p];
    const float dj = d[j];
    float mn = __builtin_inff();
#pragma unroll
    for (int kk = 0; kk < N_PTS / 64; ++kk) {
      const int k = lane + (kk << 6);
      const float dk = d[k];
      if (lab[k] != li && dk > dj) mn = fminf(mn, dk);
    }
#pragma unroll
    for (int off = 32; off; off >>= 1) mn = fminf(mn, __shfl_xor(mn, off));
    const float shn = (mn < __builtin_inff()) ? mn : neg_inside;
    losssum += fmaxf(TLMARGIN + dj - shn, 0.0f);
    pcount += 1.0f;
  }

  // ---- block reduce (all lanes of a wave hold identical values)
  __syncthreads();  // reuse red[]
  if (lane == 0) { red[wave] = losssum; red[8 + wave] = pcount; }
  __syncthreads();
  if (tid == 0) {
    float ls = 0.0f, pc = 0.0f;
#pragma unroll
    for (int w = 0; w < 8; ++w) { ls += red[w]; pc += red[8 + w]; }
    row_loss[i] = ls;
    row_cnt[i] = pc;
  }
}

__global__ __launch_bounds__(512)
void triplet_reduce(const float* __restrict__ row_loss,
                    const float* __restrict__ row_cnt,
                    float* __restrict__ out) {
  __shared__ float sl[8];
  __shared__ float sc[8];
  const int tid = threadIdx.x;
  float l = row_loss[tid];
  float c = row_cnt[tid];
#pragma unroll
  for (int off = 32; off; off >>= 1) {
    l += __shfl_xor(l, off);
    c += __shfl_xor(c, off);
  }
  const int lane = tid & 63, wave = tid >> 6;
  if (lane == 0) { sl[wave] = l; sc[wave] = c; }
  __syncthreads();
  if (tid == 0) {
    float L = 0.0f, C = 0.0f;
#pragma unroll
    for (int w = 0; w < 8; ++w) { L += sl[w]; C += sc[w]; }
    out[0] = L / C;
  }
}

extern "C" void kernel_launch(void* const* d_in, const int* in_sizes, int n_in,
                              void* d_out, int out_size, void* d_ws, size_t ws_size,
                              hipStream_t stream) {
  const float* inp = (const float*)d_in[0];
  const int* tgt = (const int*)d_in[1];
  float* out = (float*)d_out;

  float* row_loss = (float*)d_ws;          // 512 floats
  float* row_cnt  = (float*)d_ws + N_PTS;  // 512 floats

  triplet_rows<<<N_PTS, 512, 0, stream>>>(inp, tgt, row_loss, row_cnt);
  triplet_reduce<<<1, 512, 0, stream>>>(row_loss, row_cnt, out);
}

// Round 5
// 23.301 us; speedup vs baseline: 1.6404x; 1.1624x over previous
//
#include <hip/hip_runtime.h>

#define N_PTS 512
#define DIM 128
#define T4 (DIM / 4)
#define TLMARGIN 1.0f

// k0: transpose input into Tv[t4][j] (float4) and compute sq[j] = ||row j||^2.
// 64 blocks x 256 threads; each 32-lane group handles one row (coalesced reads).
__global__ __launch_bounds__(256)
void k_transpose(const float* __restrict__ inp,
                 float4* __restrict__ Tv,
                 float* __restrict__ sq) {
  const int tid = threadIdx.x;
  const int r = blockIdx.x * 8 + (tid >> 5);
  const int t4 = tid & 31;
  const float4 v = reinterpret_cast<const float4*>(inp + r * DIM)[t4];
  Tv[t4 * N_PTS + r] = v;
  float s = v.x * v.x + v.y * v.y + v.z * v.z + v.w * v.w;
#pragma unroll
  for (int off = 16; off; off >>= 1) s += __shfl_xor(s, off);
  if (t4 == 0) sq[r] = s;
}

// k1: 256 blocks x 512 threads; block b processes anchor rows {2b, 2b+1}.
// Thread j computes both dots with ONE pass over Tv column j (loads shared
// across the two rows), then per-row semi-hard mining on the LDS d-row.
__global__ __launch_bounds__(512)
void k_rows(const float* __restrict__ inp,
            const int* __restrict__ tgt,
            const float4* __restrict__ Tv,
            const float* __restrict__ sq,
            float2* __restrict__ rl) {
  const int r0 = blockIdx.x * 2;
  const int tid = threadIdx.x;
  const int lane = tid & 63;
  const int wave = tid >> 6;

  __shared__ float4 rowa[2][T4];
  __shared__ float d[2][N_PTS];
  __shared__ int lab[N_PTS];
  __shared__ float red[16];
  __shared__ unsigned long long pmask[8];
  __shared__ int plist[N_PTS];

  lab[tid] = tgt[tid];
  if (tid < 64) {
    const int rr = tid >> 5;
    const int t4 = tid & 31;
    rowa[rr][t4] = reinterpret_cast<const float4*>(inp + (r0 + rr) * DIM)[t4];
  }
  __syncthreads();

  // ---- pdist for both rows, column tid (coalesced Tv loads, no shuffles)
  const float sqj = sq[tid];
  float dot0 = 0.0f, dot1 = 0.0f;
#pragma unroll 8
  for (int t4 = 0; t4 < T4; ++t4) {
    const float4 b = Tv[t4 * N_PTS + tid];
    const float4 a0 = rowa[0][t4];
    const float4 a1 = rowa[1][t4];
    dot0 += a0.x * b.x + a0.y * b.y + a0.z * b.z + a0.w * b.w;
    dot1 += a1.x * b.x + a1.y * b.y + a1.z * b.z + a1.w * b.w;
  }
  float pd0 = fmaxf(sq[r0] + sqj - 2.0f * dot0, 0.0f);
  float pd1 = fmaxf(sq[r0 + 1] + sqj - 2.0f * dot1, 0.0f);
  if (tid == r0) pd0 = 0.0f;
  if (tid == r0 + 1) pd1 = 0.0f;
  d[0][tid] = pd0;
  d[1][tid] = pd1;
  __syncthreads();

  // ---- per-row semi-hard mining
  for (int r = 0; r < 2; ++r) {
    const int i = r0 + r;
    const int li = lab[i];

    // negatives_inside = max over negatives (row_min == 0 exactly)
    float nm = (lab[tid] != li) ? d[r][tid] : 0.0f;
#pragma unroll
    for (int off = 32; off; off >>= 1) nm = fmaxf(nm, __shfl_xor(nm, off));
    if (lane == 0) red[wave] = nm;

    const bool isPos = (lab[tid] == li) && (tid != i);
    const unsigned long long m = __ballot(isPos);
    if (lane == 0) pmask[wave] = m;
    __syncthreads();

    float neg_inside = red[0];
#pragma unroll
    for (int w = 1; w < 8; ++w) neg_inside = fmaxf(neg_inside, red[w]);

    int P = 0, rank = 0;
#pragma unroll
    for (int w = 0; w < 8; ++w) {
      const int c = __popcll(pmask[w]);
      if (w < wave) rank += c;
      P += c;
    }
    rank += __popcll(pmask[wave] & ((1ull << lane) - 1ull));
    if (isPos) plist[rank] = tid;
    __syncthreads();

    float losssum = 0.0f;
    float pcount = 0.0f;
    for (int p = wave; p < P; p += 8) {
      const int j = plist[p];
      const float dj = d[r][j];
      float mn = __builtin_inff();
#pragma unroll
      for (int kk = 0; kk < N_PTS / 64; ++kk) {
        const int k = lane + (kk << 6);
        const float dk = d[r][k];
        if (lab[k] != li && dk > dj) mn = fminf(mn, dk);
      }
#pragma unroll
      for (int off = 32; off; off >>= 1) mn = fminf(mn, __shfl_xor(mn, off));
      const float shn = (mn < __builtin_inff()) ? mn : neg_inside;
      losssum += fmaxf(TLMARGIN + dj - shn, 0.0f);
      pcount += 1.0f;
    }

    __syncthreads();  // red[] reuse
    if (lane == 0) { red[wave] = losssum; red[8 + wave] = pcount; }
    __syncthreads();
    if (tid == 0) {
      float ls = 0.0f, pc = 0.0f;
#pragma unroll
      for (int w = 0; w < 8; ++w) { ls += red[w]; pc += red[8 + w]; }
      rl[i] = make_float2(ls, pc);
    }
    __syncthreads();  // protect red[]/pmask[] before next row
  }
}

// k2: 1 block x 256 threads -> scalar loss
__global__ __launch_bounds__(256)
void k_reduce(const float2* __restrict__ rl, float* __restrict__ out) {
  __shared__ float red[8];
  const int tid = threadIdx.x;
  const float2 a = rl[tid];
  const float2 b = rl[tid + 256];
  float l = a.x + b.x;
  float c = a.y + b.y;
#pragma unroll
  for (int off = 32; off; off >>= 1) {
    l += __shfl_xor(l, off);
    c += __shfl_xor(c, off);
  }
  const int lane = tid & 63, wave = tid >> 6;
  if (lane == 0) { red[wave] = l; red[4 + wave] = c; }
  __syncthreads();
  if (tid == 0) {
    float L = 0.0f, C = 0.0f;
#pragma unroll
    for (int w = 0; w < 4; ++w) { L += red[w]; C += red[4 + w]; }
    out[0] = L / C;
  }
}

extern "C" void kernel_launch(void* const* d_in, const int* in_sizes, int n_in,
                              void* d_out, int out_size, void* d_ws, size_t ws_size,
                              hipStream_t stream) {
  const float* inp = (const float*)d_in[0];
  const int* tgt = (const int*)d_in[1];
  float* out = (float*)d_out;

  char* ws = (char*)d_ws;
  float4* Tv = (float4*)ws;                    // 256 KB
  float* sq = (float*)(ws + 262144);           // 2 KB
  float2* rl = (float2*)(ws + 262144 + 2048);  // 4 KB

  k_transpose<<<64, 256, 0, stream>>>(inp, Tv, sq);
  k_rows<<<N_PTS / 2, 512, 0, stream>>>(inp, tgt, Tv, sq, rl);
  k_reduce<<<1, 256, 0, stream>>>(rl, out);
}